// Round 4
// baseline (373.322 us; speedup 1.0000x reference)
//
#include <hip/hip_runtime.h>

#define SS 14
#define NUM_CLS 20
#define L_COORD 5.0f
#define L_NOOBJ 0.5f
#define CPB 256  // cells per block == threads per block

// d_ws layout: float acc[4] (cls, noobj, reg, contain) + uint ctr @ acc[4]

__global__ void __launch_bounds__(256) yolo_main(
    const float* __restrict__ pred,
    const float* __restrict__ tbox,
    const float* __restrict__ tcls,
    const int* __restrict__ mask,
    float* __restrict__ acc,
    float* __restrict__ out,
    int nblocks, float invN) {
  __shared__ float lp[CPB * 30];  // 30720 B: pred tile (linear)
  __shared__ float lm[CPB];       // 1024 B: mask as float
  __shared__ float4 red[4];

  const int tid = threadIdx.x;
  const size_t base = (size_t)blockIdx.x * CPB;

  // ---- register loads (independent of LDS, issue early, all coalesced) ----
  const float4* gc = (const float4*)(tcls + base * 20);  // 1280 float4/block
  float4 c0 = gc[tid];
  float4 c1 = gc[tid + 256];
  float4 c2 = gc[tid + 512];
  float4 c3 = gc[tid + 768];
  float4 c4 = gc[tid + 1024];
  float4 tb = ((const float4*)tbox)[base + tid];
  float m = mask[base + tid] ? 1.0f : 0.0f;
  lm[tid] = m;

  // ---- coalesced staging of pred tile into LDS ----
  const float4* gp = (const float4*)(pred + base * 30);  // 1920 float4/block
  float4* sp = (float4*)lp;
#pragma unroll
  for (int i = 0; i < 7; ++i) sp[tid + i * 256] = gp[tid + i * 256];
  if (tid < 128) sp[tid + 1792] = gp[tid + 1792];
  __syncthreads();

  // ---- cls loss: element-parallel over the 1280 tcls float4s ----
  float cls_c = 0.f;
#define CLSQ(cq, i)                                          \
  {                                                          \
    int e = tid + 256 * (i);                                 \
    int cell = e / 5;                                        \
    int k = e - 5 * cell;                                    \
    const float* P = lp + cell * 30 + 10 + 4 * k;            \
    float w = lm[cell];                                      \
    float d0 = P[0] - cq.x, d1 = P[1] - cq.y;                \
    float d2 = P[2] - cq.z, d3 = P[3] - cq.w;                \
    cls_c += w * (d0 * d0 + d1 * d1 + d2 * d2 + d3 * d3);    \
  }
  CLSQ(c0, 0)
  CLSQ(c1, 1)
  CLSQ(c2, 2)
  CLSQ(c3, 3)
  CLSQ(c4, 4)
#undef CLSQ

  // ---- box terms: thread t owns cell t of the tile ----
  const float* P = lp + tid * 30;
  float p0 = P[0], p1 = P[1], p2 = P[2], p3 = P[3], p4 = P[4];
  float p5 = P[5], p6 = P[6], p7 = P[7], p8 = P[8], p9 = P[9];

  float noobj_c = (1.0f - m) * (p4 * p4 + p9 * p9);

  const float invS = 1.0f / (float)SS;
  float gx0 = tb.x * invS - 0.5f * tb.z, gy0 = tb.y * invS - 0.5f * tb.w;
  float gx1 = tb.x * invS + 0.5f * tb.z, gy1 = tb.y * invS + 0.5f * tb.w;
  float ag = (gx1 - gx0) * (gy1 - gy0);

  float iou0, iou1;
  {
    float px0 = p0 * invS - 0.5f * p2, py0 = p1 * invS - 0.5f * p3;
    float px1 = p0 * invS + 0.5f * p2, py1 = p1 * invS + 0.5f * p3;
    float lx = fmaxf(px0, gx0), ly = fmaxf(py0, gy0);
    float rx = fminf(px1, gx1), ry = fminf(py1, gy1);
    float iw = fmaxf(rx - lx, 0.f), ih = fmaxf(ry - ly, 0.f);
    float inter = iw * ih;
    float ap = (px1 - px0) * (py1 - py0);
    iou0 = inter / (ap + ag - inter);
  }
  {
    float px0 = p5 * invS - 0.5f * p7, py0 = p6 * invS - 0.5f * p8;
    float px1 = p5 * invS + 0.5f * p7, py1 = p6 * invS + 0.5f * p8;
    float lx = fmaxf(px0, gx0), ly = fmaxf(py0, gy0);
    float rx = fminf(px1, gx1), ry = fminf(py1, gy1);
    float iw = fmaxf(rx - lx, 0.f), ih = fmaxf(ry - ly, 0.f);
    float inter = iw * ih;
    float ap = (px1 - px0) * (py1 - py0);
    iou1 = inter / (ap + ag - inter);
  }
  bool pick1 = (iou1 > iou0);  // jnp.argmax: first max wins ties
  float bx = pick1 ? p5 : p0;
  float by = pick1 ? p6 : p1;
  float bw = pick1 ? p7 : p2;
  float bh = pick1 ? p8 : p3;
  float bc = pick1 ? p9 : p4;

  float dx = bx - tb.x, dy = by - tb.y;
  float dw = sqrtf(bw) - sqrtf(tb.z);
  float dh = sqrtf(bh) - sqrtf(tb.w);
  float reg_c = m * (dx * dx + dy * dy + dw * dw + dh * dh);
  float dc = bc - 1.0f;
  float con_c = m * dc * dc;

  // ---- reduction: wave shuffle -> LDS -> block -> global atomics ----
  float vx = cls_c, vy = noobj_c, vz = reg_c, vw = con_c;
  for (int off = 32; off >= 1; off >>= 1) {
    vx += __shfl_down(vx, off);
    vy += __shfl_down(vy, off);
    vz += __shfl_down(vz, off);
    vw += __shfl_down(vw, off);
  }
  int wid = tid >> 6;
  if ((tid & 63) == 0) red[wid] = make_float4(vx, vy, vz, vw);
  __syncthreads();
  if (tid == 0) {
    float4 t = red[0];
#pragma unroll
    for (int i = 1; i < 4; ++i) {
      t.x += red[i].x;
      t.y += red[i].y;
      t.z += red[i].z;
      t.w += red[i].w;
    }
    atomicAdd(&acc[0], t.x);
    atomicAdd(&acc[1], t.y);
    atomicAdd(&acc[2], t.z);
    atomicAdd(&acc[3], t.w);
    __threadfence();
    unsigned prev = atomicAdd((unsigned int*)(acc + 4), 1u);
    if (prev == (unsigned)(nblocks - 1)) {
      float cls = atomicAdd(&acc[0], 0.0f) * invN;
      float noobj = L_NOOBJ * atomicAdd(&acc[1], 0.0f) * invN;
      float reg = L_COORD * atomicAdd(&acc[2], 0.0f) * invN;
      float con = atomicAdd(&acc[3], 0.0f) * invN;
      out[0] = reg + con + noobj + cls;
      out[1] = reg;
      out[2] = con;
      out[3] = noobj;
      out[4] = cls;
    }
  }
}

extern "C" void kernel_launch(void* const* d_in, const int* in_sizes, int n_in,
                              void* d_out, int out_size, void* d_ws, size_t ws_size,
                              hipStream_t stream) {
  const float* pred = (const float*)d_in[0];
  const float* tbox = (const float*)d_in[1];
  const float* tcls = (const float*)d_in[2];
  const int* mask = (const int*)d_in[3];
  float* out = (float*)d_out;
  float* acc = (float*)d_ws;

  int ncells = in_sizes[3];    // N*S*S = 802816, divisible by CPB
  int nblocks = ncells / CPB;  // 3136
  float invN = 1.0f / (float)(ncells / (SS * SS));

  hipMemsetAsync(acc, 0, 32, stream);
  yolo_main<<<nblocks, CPB, 0, stream>>>(pred, tbox, tcls, mask, acc, out, nblocks, invN);
}

// Round 5
// 203.392 us; speedup vs baseline: 1.8355x; 1.8355x over previous
//
#include <hip/hip_runtime.h>

#define SS 14
#define NUM_CLS 20
#define L_COORD 5.0f
#define L_NOOBJ 0.5f
#define CPB 256  // cells per block == threads per block

// d_ws layout: float4 part[nblocks] — per-block partial sums (cls, noobj, reg, contain)

__global__ void __launch_bounds__(256) yolo_main(
    const float* __restrict__ pred,
    const float* __restrict__ tbox,
    const float* __restrict__ tcls,
    const int* __restrict__ mask,
    float4* __restrict__ part) {
  __shared__ float lp[CPB * 30];  // 30720 B: pred tile (linear)
  __shared__ float lm[CPB];       // 1024 B: mask as float
  __shared__ float4 red[4];

  const int tid = threadIdx.x;
  const size_t base = (size_t)blockIdx.x * CPB;

  // ---- register loads (independent of LDS, issue early, all coalesced) ----
  const float4* gc = (const float4*)(tcls + base * 20);  // 1280 float4/block
  float4 c0 = gc[tid];
  float4 c1 = gc[tid + 256];
  float4 c2 = gc[tid + 512];
  float4 c3 = gc[tid + 768];
  float4 c4 = gc[tid + 1024];
  float4 tb = ((const float4*)tbox)[base + tid];
  float m = mask[base + tid] ? 1.0f : 0.0f;
  lm[tid] = m;

  // ---- coalesced staging of pred tile into LDS ----
  const float4* gp = (const float4*)(pred + base * 30);  // 1920 float4/block
  float4* sp = (float4*)lp;
#pragma unroll
  for (int i = 0; i < 7; ++i) sp[tid + i * 256] = gp[tid + i * 256];
  if (tid < 128) sp[tid + 1792] = gp[tid + 1792];
  __syncthreads();

  // ---- cls loss: element-parallel over the 1280 tcls float4s ----
  float cls_c = 0.f;
#define CLSQ(cq, i)                                          \
  {                                                          \
    int e = tid + 256 * (i);                                 \
    int cell = e / 5;                                        \
    int k = e - 5 * cell;                                    \
    const float* P = lp + cell * 30 + 10 + 4 * k;            \
    float w = lm[cell];                                      \
    float d0 = P[0] - cq.x, d1 = P[1] - cq.y;                \
    float d2 = P[2] - cq.z, d3 = P[3] - cq.w;                \
    cls_c += w * (d0 * d0 + d1 * d1 + d2 * d2 + d3 * d3);    \
  }
  CLSQ(c0, 0)
  CLSQ(c1, 1)
  CLSQ(c2, 2)
  CLSQ(c3, 3)
  CLSQ(c4, 4)
#undef CLSQ

  // ---- box terms: thread t owns cell t of the tile ----
  const float* P = lp + tid * 30;
  float p0 = P[0], p1 = P[1], p2 = P[2], p3 = P[3], p4 = P[4];
  float p5 = P[5], p6 = P[6], p7 = P[7], p8 = P[8], p9 = P[9];

  float noobj_c = (1.0f - m) * (p4 * p4 + p9 * p9);

  const float invS = 1.0f / (float)SS;
  float gx0 = tb.x * invS - 0.5f * tb.z, gy0 = tb.y * invS - 0.5f * tb.w;
  float gx1 = tb.x * invS + 0.5f * tb.z, gy1 = tb.y * invS + 0.5f * tb.w;
  float ag = (gx1 - gx0) * (gy1 - gy0);

  float iou0, iou1;
  {
    float px0 = p0 * invS - 0.5f * p2, py0 = p1 * invS - 0.5f * p3;
    float px1 = p0 * invS + 0.5f * p2, py1 = p1 * invS + 0.5f * p3;
    float lx = fmaxf(px0, gx0), ly = fmaxf(py0, gy0);
    float rx = fminf(px1, gx1), ry = fminf(py1, gy1);
    float iw = fmaxf(rx - lx, 0.f), ih = fmaxf(ry - ly, 0.f);
    float inter = iw * ih;
    float ap = (px1 - px0) * (py1 - py0);
    iou0 = inter / (ap + ag - inter);
  }
  {
    float px0 = p5 * invS - 0.5f * p7, py0 = p6 * invS - 0.5f * p8;
    float px1 = p5 * invS + 0.5f * p7, py1 = p6 * invS + 0.5f * p8;
    float lx = fmaxf(px0, gx0), ly = fmaxf(py0, gy0);
    float rx = fminf(px1, gx1), ry = fminf(py1, gy1);
    float iw = fmaxf(rx - lx, 0.f), ih = fmaxf(ry - ly, 0.f);
    float inter = iw * ih;
    float ap = (px1 - px0) * (py1 - py0);
    iou1 = inter / (ap + ag - inter);
  }
  bool pick1 = (iou1 > iou0);  // jnp.argmax: first max wins ties
  float bx = pick1 ? p5 : p0;
  float by = pick1 ? p6 : p1;
  float bw = pick1 ? p7 : p2;
  float bh = pick1 ? p8 : p3;
  float bc = pick1 ? p9 : p4;

  float dx = bx - tb.x, dy = by - tb.y;
  float dw = sqrtf(bw) - sqrtf(tb.z);
  float dh = sqrtf(bh) - sqrtf(tb.w);
  float reg_c = m * (dx * dx + dy * dy + dw * dw + dh * dh);
  float dc = bc - 1.0f;
  float con_c = m * dc * dc;

  // ---- reduction: wave shuffle -> LDS -> block partial (NO global atomics) ----
  float vx = cls_c, vy = noobj_c, vz = reg_c, vw = con_c;
  for (int off = 32; off >= 1; off >>= 1) {
    vx += __shfl_down(vx, off);
    vy += __shfl_down(vy, off);
    vz += __shfl_down(vz, off);
    vw += __shfl_down(vw, off);
  }
  int wid = tid >> 6;
  if ((tid & 63) == 0) red[wid] = make_float4(vx, vy, vz, vw);
  __syncthreads();
  if (tid == 0) {
    float4 t = red[0];
#pragma unroll
    for (int i = 1; i < 4; ++i) {
      t.x += red[i].x;
      t.y += red[i].y;
      t.z += red[i].z;
      t.w += red[i].w;
    }
    part[blockIdx.x] = t;  // contention-free store
  }
}

__global__ void __launch_bounds__(256) yolo_reduce(
    const float4* __restrict__ part, float* __restrict__ out,
    int nblocks, float invN) {
  const int tid = threadIdx.x;
  float vx = 0.f, vy = 0.f, vz = 0.f, vw = 0.f;
  for (int i = tid; i < nblocks; i += 256) {
    float4 t = part[i];
    vx += t.x;
    vy += t.y;
    vz += t.z;
    vw += t.w;
  }
  for (int off = 32; off >= 1; off >>= 1) {
    vx += __shfl_down(vx, off);
    vy += __shfl_down(vy, off);
    vz += __shfl_down(vz, off);
    vw += __shfl_down(vw, off);
  }
  __shared__ float4 red[4];
  int wid = tid >> 6;
  if ((tid & 63) == 0) red[wid] = make_float4(vx, vy, vz, vw);
  __syncthreads();
  if (tid == 0) {
    float4 t = red[0];
#pragma unroll
    for (int i = 1; i < 4; ++i) {
      t.x += red[i].x;
      t.y += red[i].y;
      t.z += red[i].z;
      t.w += red[i].w;
    }
    float cls = t.x * invN;
    float noobj = L_NOOBJ * t.y * invN;
    float reg = L_COORD * t.z * invN;
    float con = t.w * invN;
    out[0] = reg + con + noobj + cls;
    out[1] = reg;
    out[2] = con;
    out[3] = noobj;
    out[4] = cls;
  }
}

extern "C" void kernel_launch(void* const* d_in, const int* in_sizes, int n_in,
                              void* d_out, int out_size, void* d_ws, size_t ws_size,
                              hipStream_t stream) {
  const float* pred = (const float*)d_in[0];
  const float* tbox = (const float*)d_in[1];
  const float* tcls = (const float*)d_in[2];
  const int* mask = (const int*)d_in[3];
  float* out = (float*)d_out;
  float4* part = (float4*)d_ws;

  int ncells = in_sizes[3];    // N*S*S = 802816, divisible by CPB
  int nblocks = ncells / CPB;  // 3136
  float invN = 1.0f / (float)(ncells / (SS * SS));

  yolo_main<<<nblocks, CPB, 0, stream>>>(pred, tbox, tcls, mask, part);
  yolo_reduce<<<1, 256, 0, stream>>>(part, out, nblocks, invN);
}